// Round 9
// baseline (43529.807 us; speedup 1.0000x reference)
//
#include <hip/hip_runtime.h>

#define B_    128
#define T_    200
#define TE_   256
#define H_    256
#define PRE_  128
#define OUT_  400
#define BT_   (B_*T_)          // 25600

__device__ __forceinline__ float sigm_(float x){ return 1.f/(1.f+__expf(-x)); }
__device__ __forceinline__ float tanh_(float x){
  x = fminf(15.f, fmaxf(-15.f, x));
  float e = __expf(2.f*x);
  return 1.f - 2.f/(e+1.f);
}
__device__ __forceinline__ float b2f_lo(unsigned u){ return __uint_as_float(u << 16); }
__device__ __forceinline__ float b2f_hi(unsigned u){ return __uint_as_float(u & 0xffff0000u); }
__device__ __forceinline__ unsigned short f2b(float f){
  unsigned u = __float_as_uint(f);
  unsigned r = (u + 0x7fff + ((u >> 16) & 1)) >> 16;   // RNE
  return (unsigned short)r;
}

// packed u4 = rows{2kp,2kp+1} x cols{4jq..4jq+3}; u16 pos = (k&1)*4 + (j&3)
__device__ __forceinline__ void pk8(float&a0,float&a1,float&a2,float&a3,
                                    const uint4 w, const float x0, const float x1){
  a0=fmaf(x0,b2f_lo(w.x),a0); a1=fmaf(x0,b2f_hi(w.x),a1);
  a2=fmaf(x0,b2f_lo(w.y),a2); a3=fmaf(x0,b2f_hi(w.y),a3);
  a0=fmaf(x1,b2f_lo(w.z),a0); a1=fmaf(x1,b2f_hi(w.z),a1);
  a2=fmaf(x1,b2f_lo(w.w),a2); a3=fmaf(x1,b2f_hi(w.w),a3);
}

// ---------------- fp32 transpose (prologue/epilogue GEMM weights) ----------------
struct TD { const float* src; float* dst; int N; int Ksrc; int col0; int Keff; int blk0; };
struct TDs { TD d[5]; };

__global__ __launch_bounds__(256) void transpose_cast(TDs P)
{
  int bid = blockIdx.x, m = 0;
#pragma unroll
  for (int i = 1; i < 5; ++i) if (bid >= P.d[i].blk0) m = i;
  TD t = P.d[m];
  long gid = (long)(bid - t.blk0)*256 + threadIdx.x;
  long nk = (long)t.N * t.Keff;
  if (gid >= nk) return;
  int k = (int)(gid / t.N);
  int j = (int)(gid % t.N);
  t.dst[(size_t)k*t.N + j] = t.src[(size_t)j*t.Ksrc + t.col0 + k];
}

// ---------------- bf16 weight repack into k-pair/col-quad uint4 layout ----------------
struct WP { const float* src; int dstoff_u4; int fmt3; int col0; int srcK; int blk0; };
struct WPs { WP d[9]; };

__global__ __launch_bounds__(256) void wpack(WPs P, unsigned short* __restrict__ dst)
{
  int bid = blockIdx.x, m = 0;
#pragma unroll
  for (int i = 1; i < 9; ++i) if (bid >= P.d[i].blk0) m = i;
  WP t = P.d[m];
  int idx = (bid - t.blk0)*256 + threadIdx.x;
  int total = t.fmt3 ? 196608 : 65536;
  if (idx >= total) return;
  int kp, jq, w8;
  if (t.fmt3){ kp = idx/1536; int rem = idx - kp*1536; jq = rem>>3; w8 = rem&7; }
  else       { kp = idx>>9;   int rem = idx&511;       jq = rem>>3; w8 = rem&7; }
  int k = kp*2 + (w8>>2);
  int j = jq*4 + (w8&3);
  dst[(size_t)t.dstoff_u4*8 + idx] = f2b(t.src[(size_t)j*t.srcK + t.col0 + k]);
}

// ---------------- generic tiled GEMM: C = act(A[M,K] @ WT[K,N] + bias) ----------------
// AMODE: 0 = plain fp32 (lda), 1 = teacher-forced prev-frame loader
// OUTMODE: 0 = fp32 row-major, 3 = pm bf16 [b][h][te] store
template<int AMODE, bool RELU, int OUTMODE>
__global__ __launch_bounds__(256) void gemm_k(const float* __restrict__ A, int lda,
                                              const float* __restrict__ WT, int N, int K,
                                              const float* __restrict__ bias,
                                              float* __restrict__ C)
{
  const int tid  = threadIdx.x;
  const int row0 = blockIdx.x * 64;
  const int n0   = blockIdx.y * 64;
  __shared__ float As[16][68];
  __shared__ float Bs[16][64];
  const int tx = tid & 15, ty = tid >> 4;
  float acc[4][4];
#pragma unroll
  for (int i = 0; i < 4; ++i)
#pragma unroll
    for (int j = 0; j < 4; ++j) acc[i][j] = 0.f;

  for (int k0 = 0; k0 < K; k0 += 16){
#pragma unroll
    for (int ll = 0; ll < 4; ++ll){
      int idx = tid + ll*256;
      int m2 = idx >> 4, kk = idx & 15;
      float v;
      if (AMODE == 1){
        int r = row0 + m2;
        int t = r % T_;
        v = (t == 0) ? 0.f : A[(size_t)(r-1)*OUT_ + k0 + kk];
      } else {
        v = A[(size_t)(row0+m2)*lda + k0 + kk];
      }
      As[kk][m2] = v;
    }
#pragma unroll
    for (int ll = 0; ll < 4; ++ll){
      int idx = tid + ll*256;
      int kk = idx >> 6, j = idx & 63;
      int jg = n0 + j;
      Bs[kk][j] = (jg < N) ? WT[(size_t)(k0+kk)*N + jg] : 0.f;
    }
    __syncthreads();
#pragma unroll
    for (int kk = 0; kk < 16; ++kk){
      float4 a4 = *(const float4*)&As[kk][ty*4];
      float4 b4 = *(const float4*)&Bs[kk][tx*4];
      acc[0][0] = fmaf(a4.x, b4.x, acc[0][0]); acc[0][1] = fmaf(a4.x, b4.y, acc[0][1]);
      acc[0][2] = fmaf(a4.x, b4.z, acc[0][2]); acc[0][3] = fmaf(a4.x, b4.w, acc[0][3]);
      acc[1][0] = fmaf(a4.y, b4.x, acc[1][0]); acc[1][1] = fmaf(a4.y, b4.y, acc[1][1]);
      acc[1][2] = fmaf(a4.y, b4.z, acc[1][2]); acc[1][3] = fmaf(a4.y, b4.w, acc[1][3]);
      acc[2][0] = fmaf(a4.z, b4.x, acc[2][0]); acc[2][1] = fmaf(a4.z, b4.y, acc[2][1]);
      acc[2][2] = fmaf(a4.z, b4.z, acc[2][2]); acc[2][3] = fmaf(a4.z, b4.w, acc[2][3]);
      acc[3][0] = fmaf(a4.w, b4.x, acc[3][0]); acc[3][1] = fmaf(a4.w, b4.y, acc[3][1]);
      acc[3][2] = fmaf(a4.w, b4.z, acc[3][2]); acc[3][3] = fmaf(a4.w, b4.w, acc[3][3]);
    }
    __syncthreads();
  }
#pragma unroll
  for (int i = 0; i < 4; ++i){
    int r = row0 + ty*4 + i;
#pragma unroll
    for (int jj = 0; jj < 4; ++jj){
      int c = n0 + tx*4 + jj;
      if (c < N){
        float v = acc[i][jj] + (bias ? bias[c] : 0.f);
        if (RELU) v = fmaxf(v, 0.f);
        if (OUTMODE == 0){
          C[(size_t)r*N + c] = v;
        } else {
          int bb = r >> 8, te = r & 255;
          ((unsigned short*)C)[(size_t)bb*65536 + (size_t)c*256 + te] = f2b(v);
        }
      }
    }
  }
}

// ---------------- persistent decoder: 256 WGs, WG = (batch b, te-half) ----------------
// wpk u4 offsets: awihA 0 | awhh 24576 | g1whh 49152 | g2whh 73728 |
//                 g1wih 98304 | g2wih 122880 | wq 147456 | wpA 155648 | wpB 163840
struct DP {
  const float *preGI;
  const uint4 *wpk;
  const unsigned short *pm16;
  const float *enc;
  const float *abhh, *g1bih, *g1bhh, *g2bih, *g2bhh, *bp, *v_attn;
  float *decbuf, *aln;
  float *pay;            // [256][260]
  unsigned int *flag;    // [256][200]
};

// 8-load straight-line block for the 768-wide matvecs (stride 192 u4)
#define LD8_192(q) uint4 w0=q[0],w1=q[192],w2=q[384],w3=q[576],w4=q[768],w5=q[960],w6=q[1152],w7=q[1344]
#define LD8_64(q)  uint4 w0=q[0],w1=q[64], w2=q[128],w3=q[192],w4=q[256],w5=q[320],w6=q[384], w7=q[448]
#define PK8X(xp) \
  { float4 x0=*(const float4*)(xp), x1=*(const float4*)((xp)+4); \
    float4 x2=*(const float4*)((xp)+8), x3=*(const float4*)((xp)+12); \
    pk8(a0,a1,a2,a3, w0, x0.x,x0.y); pk8(a0,a1,a2,a3, w1, x0.z,x0.w); \
    pk8(a0,a1,a2,a3, w2, x1.x,x1.y); pk8(a0,a1,a2,a3, w3, x1.z,x1.w); \
    pk8(a0,a1,a2,a3, w4, x2.x,x2.y); pk8(a0,a1,a2,a3, w5, x2.z,x2.w); \
    pk8(a0,a1,a2,a3, w6, x3.x,x3.y); pk8(a0,a1,a2,a3, w7, x3.z,x3.w); }

__global__ __launch_bounds__(1024, 4) void decoder_kernel(DP P)
{
  const int tid  = threadIdx.x;
  const int bid  = blockIdx.x;        // 0..255
  const int b    = bid & 127;
  const int half = bid >> 7;
  const int pbid = bid ^ 128;         // partner (same XCD under %8 round-robin)

  __shared__ __align__(16) unsigned short s_pm[32768];   // [h][128 te']
  __shared__ __align__(16) unsigned short s_enc[32768];  // [128 te'][h]
  __shared__ __align__(16) float s_gi[768], s_gh[768], s_g1h[768], s_g2h[768];
  __shared__ __align__(16) float s_part[2304];           // partials; dq at [2048..2303]
  __shared__ __align__(16) float s_ah[256], s_h1[256], s_h2[256], s_av[256], s_dec[256], s_q[256];
  __shared__ __align__(16) float s_alx[128], s_v[256];
  __shared__ float s_red[2];

  // ---- load pm-half into LDS (bf16, [h][te']) ----
  {
    const unsigned int* pm32 = (const unsigned int*)(P.pm16);
    unsigned int* d32 = (unsigned int*)s_pm;
#pragma unroll
    for (int i = 0; i < 16; ++i){
      int L = i*1024 + tid;                 // 16384 u32
      int h = L >> 6, tp = L & 63;
      d32[L] = pm32[(size_t)b*32768 + (size_t)h*128 + half*64 + tp];
    }
  }
  // ---- load enc-half into LDS (fp32 -> bf16, [te'][h]) ----
  {
    const float* eb = P.enc + (size_t)b*65536 + (size_t)half*128*256;
#pragma unroll
    for (int i = 0; i < 32; ++i){
      int L = i*1024 + tid;                 // 32768 elems
      s_enc[L] = f2b(eb[L]);
    }
  }

  // ---- per-role constants ----
  // P1 matvec threads: tid>=256 : m=(tid-256)/192, jq=(tid-256)%192
  const int p1m  = (tid >= 256) ? (tid-256)/192 : 0;
  const int p1jq = (tid >= 256) ? (tid-256)%192 : 0;
  const uint4* p1base = P.wpk + ((p1m==0)? 0 : (p1m==1)? 24576 : (p1m==2)? 49152 : 73728) + p1jq;
  const float* p1x  = (p1m==0)? s_av : (p1m==1)? s_ah : (p1m==2)? s_h1 : s_h2;
  float*       p1out= (p1m==0)? s_gi : (p1m==1)? s_gh : (p1m==2)? s_g1h : s_g2h;
  float4 p1bias = make_float4(0.f,0.f,0.f,0.f);
  if (tid >= 256){
    const float* bsrc = (p1m==1)? P.abhh : (p1m==2)? P.g1bhh : (p1m==3)? P.g2bhh : nullptr;
    if (bsrc) p1bias = *(const float4*)(bsrc + p1jq*4);
  }
  // gate-thread biases
  float r_1bi0=0,r_1bi1=0,r_1bi2=0, r_2bi0=0,r_2bi1=0,r_2bi2=0, r_bp=0;
  if (tid < 256){
    r_1bi0=P.g1bih[tid]; r_1bi1=P.g1bih[256+tid]; r_1bi2=P.g1bih[512+tid];
    r_2bi0=P.g2bih[tid]; r_2bi1=P.g2bih[256+tid]; r_2bi2=P.g2bih[512+tid];
    r_bp=P.bp[tid];
    s_v[tid]=P.v_attn[tid];
    s_ah[tid]=0.f; s_h1[tid]=0.f; s_h2[tid]=0.f; s_av[tid]=0.f;
  }
  __syncthreads();

  const float* pregb = P.preGI + (size_t)b*T_*768;
  float* aln_b = P.aln    + (size_t)b*T_*TE_;
  float* dec_b = P.decbuf + (size_t)b*T_*H_;
  float* payme = P.pay + (size_t)bid*260;
  float* paypr = P.pay + (size_t)pbid*260;
  unsigned int* flme = P.flag + (size_t)bid*T_;
  unsigned int* flpr = P.flag + (size_t)pbid*T_;

  const int kg8 = tid >> 6, jt8 = tid & 63;

  for (int t = 0; t < T_; ++t){
    float pr0=0.f, pr1=0.f, pr2=0.f;
    // ==== P1: four 768-wide matvecs (col-quad per thread, 12 waves) + preg (tid<256) ====
    if (tid < 256){
      const float* pg = pregb + (size_t)t*768 + tid;
      pr0 = pg[0]; pr1 = pg[256]; pr2 = pg[512];
    } else {
      float a0=p1bias.x, a1=p1bias.y, a2=p1bias.z, a3=p1bias.w;
      const uint4* p = p1base;
#pragma unroll
      for (int blk = 0; blk < 16; ++blk){
        LD8_192(p); p += 1536;
        PK8X(p1x + blk*16);
      }
      *(float4*)(p1out + p1jq*4) = make_float4(a0,a1,a2,a3);
    }
    __syncthreads();                                   // B1
    // ==== C1: attention-GRU gate ====
    if (tid < 256){
      float gi0 = s_gi[tid]+pr0, gi1 = s_gi[256+tid]+pr1, gi2 = s_gi[512+tid]+pr2;
      float r = sigm_(gi0 + s_gh[tid]), z = sigm_(gi1 + s_gh[256+tid]);
      float n = tanh_(gi2 + r*s_gh[512+tid]);
      s_ah[tid] = (1.f-z)*n + z*s_ah[tid];
    }
    __syncthreads();                                   // B2
    // ==== P2: wq@ah (tid<256), wpA@ah (tid 256..511); 4-way K-split ====
    if (tid < 512){
      const int m = tid >> 8, s = tid & 255, kg = s >> 6, jq = s & 63;
      const uint4* base = P.wpk + (m ? 155648 : 147456) + (size_t)kg*2048 + jq;
      const float* xk = s_ah + kg*64;
      float a0=0,a1=0,a2=0,a3=0;
#pragma unroll
      for (int blk = 0; blk < 4; ++blk){
        const uint4* q = base + blk*512;
        LD8_64(q);
        PK8X(xk + blk*16);
      }
      *(float4*)(s_part + m*1024 + kg*256 + jq*4) = make_float4(a0,a1,a2,a3);
    }
    __syncthreads();                                   // B3
    if (tid < 256){
      s_q[tid] = s_part[tid] + s_part[256+tid] + s_part[512+tid] + s_part[768+tid];
    } else if (tid < 512){
      int j = tid - 256;
      s_part[2048+j] = s_part[1024+j] + s_part[1280+j] + s_part[1536+j] + s_part[1792+j];
    }
    __syncthreads();                                   // B4
    // ==== P3: scores from LDS pm-half (all 1024; kg owns 16 h, jt owns te' pair) ====
    {
      const unsigned int* pmrow = (const unsigned int*)s_pm;
      float e0=0.f, e1=0.f;
      int h0 = kg8*16;
#pragma unroll
      for (int i = 0; i < 16; ++i){
        int h = h0 + i;
        unsigned int pv = pmrow[h*64 + jt8];
        float qh = s_q[h], vh = s_v[h];
        e0 = fmaf(vh, tanh_(b2f_lo(pv)+qh), e0);
        e1 = fmaf(vh, tanh_(b2f_hi(pv)+qh), e1);
      }
      s_part[kg8*128 + jt8*2]   = e0;
      s_part[kg8*128 + jt8*2+1] = e1;
    }
    __syncthreads();                                   // B5
    if (tid < 128){
      float e = 0.f;
#pragma unroll
      for (int g = 0; g < 16; ++g) e += s_part[g*128 + tid];
      float ex = __expf(e);
      s_alx[tid] = ex;
      float s = ex;
      for (int o = 32; o; o >>= 1) s += __shfl_down(s, o, 64);
      if ((tid & 63) == 0) s_red[tid >> 6] = s;
    }
    __syncthreads();                                   // B6
    // ==== P4: context partial from LDS enc-half (all 1024; kg owns 32 te', j owns h) ====
    {
      const int kg = tid >> 8, j = tid & 255;
      float a = 0.f;
#pragma unroll
      for (int i = 0; i < 32; ++i){
        int te = kg*32 + i;
        a = fmaf(s_alx[te], b2f_lo((unsigned)s_enc[te*256 + j] << 16 >> 16 ? (unsigned)s_enc[te*256+j] : (unsigned)s_enc[te*256+j]), a);
      }
      // (b2f from u16: value = u16<<16 reinterpret)
      s_part[kg*256 + j] = a;
    }
    __syncthreads();                                   // B7
    // ==== C4: av partial + EXCHANGE ====
    float avp = 0.f;
    if (tid < 256){
      avp = s_part[tid] + s_part[256+tid] + s_part[512+tid] + s_part[768+tid];
      __hip_atomic_store(&payme[tid], avp, __ATOMIC_RELAXED, __HIP_MEMORY_SCOPE_AGENT);
    }
    if (tid == 0)
      __hip_atomic_store(&payme[256], s_red[0]+s_red[1], __ATOMIC_RELAXED, __HIP_MEMORY_SCOPE_AGENT);
    __syncthreads();                                   // B8 (payload complete)
    if (tid == 0){
      __hip_atomic_store(&flme[t], 1u, __ATOMIC_RELEASE, __HIP_MEMORY_SCOPE_AGENT);
      while (__hip_atomic_load(&flpr[t], __ATOMIC_ACQUIRE, __HIP_MEMORY_SCOPE_AGENT) == 0u)
        __builtin_amdgcn_s_sleep(2);
    }
    __syncthreads();                                   // B9 (partner payload visible)
    {
      float psum = __hip_atomic_load(&paypr[256], __ATOMIC_RELAXED, __HIP_MEMORY_SCOPE_AGENT);
      float inv = 1.f / (s_red[0] + s_red[1] + psum);
      if (tid < 256){
        float pav = __hip_atomic_load(&paypr[tid], __ATOMIC_RELAXED, __HIP_MEMORY_SCOPE_AGENT);
        s_av[tid] = (avp + pav) * inv;
      }
      if (tid < 128)
        aln_b[(size_t)t*TE_ + half*128 + tid] = s_alx[tid] * inv;
    }
    __syncthreads();                                   // B10
    // ==== P5: wpB@av (tid<256; 4-way K-split) ====
    if (tid < 256){
      const int kg = tid >> 6, jq = tid & 63;
      const uint4* base = P.wpk + 163840 + (size_t)kg*2048 + jq;
      const float* xk = s_av + kg*64;
      float a0=0,a1=0,a2=0,a3=0;
#pragma unroll
      for (int blk = 0; blk < 4; ++blk){
        const uint4* q = base + blk*512;
        LD8_64(q);
        PK8X(xk + blk*16);
      }
      *(float4*)(s_part + kg*256 + jq*4) = make_float4(a0,a1,a2,a3);
    }
    __syncthreads();                                   // B11
    if (tid < 256){
      s_dec[tid] = s_part[2048+tid] + r_bp
                 + s_part[tid] + s_part[256+tid] + s_part[512+tid] + s_part[768+tid];
    }
    __syncthreads();                                   // B12
    // ==== P6: g1wih@dec (tid<384; 2-way K-split) ====
    if (tid < 384){
      const int kg = tid/192, jq = tid%192;
      const uint4* base = P.wpk + 98304 + (size_t)kg*12288 + jq;
      const float* xk = s_dec + kg*128;
      float a0=0,a1=0,a2=0,a3=0;
#pragma unroll
      for (int blk = 0; blk < 8; ++blk){
        const uint4* q = base + blk*1536;
        LD8_192(q);
        PK8X(xk + blk*16);
      }
      *(float4*)(s_part + kg*768 + jq*4) = make_float4(a0,a1,a2,a3);
    }
    __syncthreads();                                   // B13
    if (tid < 256){
      float gi0 = s_part[tid]     + s_part[768+tid]  + r_1bi0;
      float gi1 = s_part[256+tid] + s_part[1024+tid] + r_1bi1;
      float gi2 = s_part[512+tid] + s_part[1280+tid] + r_1bi2;
      float r = sigm_(gi0 + s_g1h[tid]), z = sigm_(gi1 + s_g1h[256+tid]);
      float n = tanh_(gi2 + r*s_g1h[512+tid]);
      float h1n = (1.f-z)*n + z*s_h1[tid];
      s_h1[tid] = h1n;
      s_dec[tid] += h1n;
    }
    __syncthreads();                                   // B14
    // ==== P7: g2wih@dec2 (tid<384) ====
    if (tid < 384){
      const int kg = tid/192, jq = tid%192;
      const uint4* base = P.wpk + 122880 + (size_t)kg*12288 + jq;
      const float* xk = s_dec + kg*128;
      float a0=0,a1=0,a2=0,a3=0;
#pragma unroll
      for (int blk = 0; blk < 8; ++blk){
        const uint4* q = base + blk*1536;
        LD8_192(q);
        PK8X(xk + blk*16);
      }
      *(float4*)(s_part + kg*768 + jq*4) = make_float4(a0,a1,a2,a3);
    }
    __syncthreads();                                   // B15
    if (tid < 256){
      float gi0 = s_part[tid]     + s_part[768+tid]  + r_2bi0;
      float gi1 = s_part[256+tid] + s_part[1024+tid] + r_2bi1;
      float gi2 = s_part[512+tid] + s_part[1280+tid] + r_2bi2;
      float r = sigm_(gi0 + s_g2h[tid]), z = sigm_(gi1 + s_g2h[256+tid]);
      float n = tanh_(gi2 + r*s_g2h[512+tid]);
      float h2n = (1.f-z)*n + z*s_h2[tid];
      s_h2[tid] = h2n;
      float d = s_dec[tid] + h2n;
      s_dec[tid] = d;
      if (half == 0) dec_b[(size_t)t*H_ + tid] = d;
    }
    __syncthreads();                                   // B16
  }
}

// ---------------- host ----------------
extern "C" void kernel_launch(void* const* d_in, const int* in_sizes, int n_in,
                              void* d_out, int out_size, void* d_ws, size_t ws_size,
                              hipStream_t stream)
{
  const float* enc   = (const float*)d_in[0];
  const float* tgt   = (const float*)d_in[1];
  const float* pw1   = (const float*)d_in[2];
  const float* pb1   = (const float*)d_in[3];
  const float* pw2   = (const float*)d_in[4];
  const float* pb2   = (const float*)d_in[5];
  const float* awih  = (const float*)d_in[6];
  const float* awhh  = (const float*)d_in[7];
  const float* abih  = (const float*)d_in[8];
  const float* abhh  = (const float*)d_in[9];
  const float* wq    = (const float*)d_in[10];
  const float* wm    = (const float*)d_in[11];
  const float* vat   = (const float*)d_in[12];
  const float* wp    = (const float*)d_in[13];
  const float* bp    = (const float*)d_in[14];
  const float* g1wih = (const float*)d_in[15];
  const float* g1whh = (const float*)d_in[16];
  const float* g1bih = (const float*)d_in[17];
  const float* g1bhh = (const float*)d_in[18];
  const float* g2wih = (const float*)d_in[19];
  const float* g2whh = (const float*)d_in[20];
  const float* g2bih = (const float*)d_in[21];
  const float* g2bhh = (const float*)d_in[22];
  const float* wo    = (const float*)d_in[23];
  const float* bo    = (const float*)d_in[24];

  float* ws = (float*)d_ws;
  size_t off = 0;
  auto alloc = [&](size_t n){ float* p = ws + off; off += (n + 3) & ~(size_t)3; return p; };

  float* wmT    = alloc(65536);
  float* w1T    = alloc(102400);
  float* w2T    = alloc(32768);
  float* awihPT = alloc(98304);
  float* woT    = alloc(102400);
  float* wpkf   = alloc(688128);                 // 172032 uint4
  float* pmpkf  = alloc(4194304);                // bf16 [b][h][te]
  float* payf   = alloc(256*260);
  float* flagf  = alloc(256*T_);
  float* decb   = alloc((size_t)BT_*H_);
  float* p2f    = alloc((size_t)BT_*PRE_);
  float* preGIf = alloc((size_t)BT_*3*H_);
  float* p1f = decb;

  // ---- 1. fp32 transposes ----
  TDs td;
  const float* tsr[5] = { wm,  pw1, pw2, awih, wo  };
  float* tds[5]       = { wmT, w1T, w2T, awihPT, woT };
  int   tN[5]  = { 256, 256, 128, 768, 400 };
  int   tK[5]  = { 256, 400, 256, 384, 256 };
  int   tc[5]  = { 0,   0,   0,   0,   0   };
  int   tE[5]  = { 256, 400, 256, 128, 256 };
  int blk = 0;
  for (int i = 0; i < 5; ++i){
    td.d[i] = { tsr[i], tds[i], tN[i], tK[i], tc[i], tE[i], blk };
    blk += (int)(((long)tN[i]*tE[i] + 255) / 256);
  }
  transpose_cast<<<blk, 256, 0, stream>>>(td);

  // ---- 2. bf16 packed weights ----
  WPs wp_;
  const float* wsr[9] = { awih,  awhh,  g1whh, g2whh, g1wih, g2wih,  wq,     wp,     wp };
  int wdo[9] = { 0,     24576, 49152, 73728, 98304, 122880, 147456, 155648, 163840 };
  int wf3[9] = { 1,     1,     1,     1,     1,     1,      0,      0,      0 };
  int wc0[9] = { 128,   0,     0,     0,     0,     0,      0,      0,      256 };
  int wsk[9] = { 384,   256,   256,   256,   256,   256,    256,    512,    512 };
  int wblk = 0;
  for (int i = 0; i < 9; ++i){
    wp_.d[i] = { wsr[i], wdo[i], wf3[i], wc0[i], wsk[i], wblk };
    wblk += (wf3[i] ? 196608 : 65536) / 256;
  }
  wpack<<<wblk, 256, 0, stream>>>(wp_, (unsigned short*)wpkf);

  // ---- 3. prenet + preGI ----
  gemm_k<1, true,  0><<<dim3(BT_/64, 4), 256, 0, stream>>>(tgt, 0,   w1T,    256, 400, pb1,  p1f);
  gemm_k<0, true,  0><<<dim3(BT_/64, 2), 256, 0, stream>>>(p1f, 256, w2T,    128, 256, pb2,  p2f);
  gemm_k<0, false, 0><<<dim3(BT_/64,12), 256, 0, stream>>>(p2f, 128, awihPT, 768, 128, abih, preGIf);
  // ---- 4. pm = enc @ wm.T, bf16 [b][h][te] ----
  gemm_k<0, false, 3><<<dim3((B_*TE_)/64, 4), 256, 0, stream>>>(enc, 256, wmT, 256, 256, nullptr, pmpkf);

  // ---- 5. zero exchange flags (replay-safe), then recurrence ----
  hipMemsetAsync(flagf, 0, 256*T_*4, stream);
  DP P;
  P.preGI = preGIf;
  P.wpk = (const uint4*)wpkf; P.pm16 = (const unsigned short*)pmpkf; P.enc = enc;
  P.abhh = abhh; P.g1bih = g1bih; P.g1bhh = g1bhh; P.g2bih = g2bih; P.g2bhh = g2bhh;
  P.bp = bp; P.v_attn = vat;
  P.decbuf = decb;
  P.aln = (float*)d_out + (size_t)BT_*OUT_;
  P.pay = payf; P.flag = (unsigned int*)flagf;
  decoder_kernel<<<256, 1024, 0, stream>>>(P);

  // ---- 6. deferred output projection ----
  gemm_k<0, false, 0><<<dim3(BT_/64, 7), 256, 0, stream>>>(decb, 256, woT, 400, 256, bo, (float*)d_out);
}